// Round 5
// baseline (199.153 us; speedup 1.0000x reference)
//
#include <hip/hip_runtime.h>
#include <hip/hip_bf16.h>

// out[n, d] = x[n, d] * w[d]   (N=200000, D=512, fp32)
// HBM-bound stream. 16B/lane f32x4, 4x unrolled independent loads for
// memory-level parallelism, weight hoisted (stride % 128 == 0).
// R5 ablation: NO nontemporal builtins (R4 regression 165->186us suspected
// from nt stores defeating L2 write aggregation).

typedef float f32x4 __attribute__((ext_vector_type(4)));

__global__ __launch_bounds__(256) void colscale_kernel(
    const f32x4* __restrict__ x4,
    const f32x4* __restrict__ w4,    // 128 f32x4 (512 floats)
    f32x4* __restrict__ out4,
    long long n4,                    // total f32x4 count
    long long nfull)                 // multiple of 4*stride, <= n4
{
    const long long i0     = (long long)blockIdx.x * blockDim.x + threadIdx.x;
    const long long stride = (long long)gridDim.x * blockDim.x;   // multiple of 128
    const long long big    = stride * 4;

    // (i0 + k*stride) & 127 == i0 & 127 for all k  -> load weight once.
    const f32x4 w = w4[(int)(i0 & 127)];

    for (long long i = i0; i < nfull; i += big) {
        f32x4 v0 = x4[i];
        f32x4 v1 = x4[i + stride];
        f32x4 v2 = x4[i + 2 * stride];
        f32x4 v3 = x4[i + 3 * stride];
        v0 *= w;
        v1 *= w;
        v2 *= w;
        v3 *= w;
        out4[i]              = v0;
        out4[i + stride]     = v1;
        out4[i + 2 * stride] = v2;
        out4[i + 3 * stride] = v3;
    }

    // Tail: [nfull, n4). nfull % 128 == 0 so weight idx is still i0 & 127.
    for (long long i = nfull + i0; i < n4; i += stride) {
        f32x4 v = x4[i];
        v *= w;
        out4[i] = v;
    }
}

extern "C" void kernel_launch(void* const* d_in, const int* in_sizes, int n_in,
                              void* d_out, int out_size, void* d_ws, size_t ws_size,
                              hipStream_t stream) {
    const f32x4* x4 = (const f32x4*)d_in[0];            // x: [N, D] fp32
    const f32x4* w4 = (const f32x4*)d_in[1];            // weight_local: [D,1] fp32
    f32x4* out4 = (f32x4*)d_out;

    long long n4 = (long long)out_size / 4;             // 25,600,000

    const int block = 256;
    const int grid  = 2048;                              // 2048*256 = 524288, %128==0
    const long long stride = (long long)grid * block;
    const long long big    = stride * 4;
    const long long nfull  = (n4 / big) * big;

    colscale_kernel<<<grid, block, 0, stream>>>(x4, w4, out4, n4, nfull);
}

// Round 6
// 139.126 us; speedup vs baseline: 1.4315x; 1.4315x over previous
//
#include <hip/hip_runtime.h>
#include <hip/hip_bf16.h>

// out[n, d] = x[n, d] * w[d]   (N=200000, D=512, fp32)
// HBM-bound stream. BabelStream-style exact-fit: ONE f32x4 per thread,
// no loop (n4 = 25.6M = 100000 blocks x 256 threads exactly).
// R4/R5 showed strided 4x unrolling REGRESSES (165 -> 186/199 us): spreading
// a thread's accesses 8MB apart hurts DRAM locality. Simplest wins.

typedef float f32x4 __attribute__((ext_vector_type(4)));

__global__ __launch_bounds__(256) void colscale_kernel(
    const f32x4* __restrict__ x4,
    const f32x4* __restrict__ w4,    // 128 f32x4 (512 floats), L1/L2 resident
    f32x4* __restrict__ out4,
    long long n4)
{
    long long i = (long long)blockIdx.x * blockDim.x + threadIdx.x;
    if (i < n4) {
        f32x4 v = x4[i];
        v *= w4[(int)(i & 127)];
        out4[i] = v;
    }
}

extern "C" void kernel_launch(void* const* d_in, const int* in_sizes, int n_in,
                              void* d_out, int out_size, void* d_ws, size_t ws_size,
                              hipStream_t stream) {
    const f32x4* x4 = (const f32x4*)d_in[0];            // x: [N, D] fp32
    const f32x4* w4 = (const f32x4*)d_in[1];            // weight_local: [D,1] fp32
    f32x4* out4 = (f32x4*)d_out;

    long long n4 = (long long)out_size / 4;             // 25,600,000
    const int block = 256;
    long long grid = (n4 + block - 1) / block;          // 100000 exactly

    colscale_kernel<<<(int)grid, block, 0, stream>>>(x4, w4, out4, n4);
}

// Round 7
// 128.355 us; speedup vs baseline: 1.5516x; 1.0839x over previous
//
#include <hip/hip_runtime.h>
#include <hip/hip_bf16.h>

// out[n, d] = x[n, d] * w[d]   (N=200000, D=512, fp32)
// HBM-bound stream. BabelStream-style exact-fit: ONE f32x4 per thread,
// no loop (n4 = 25.6M = 100000 blocks x 256 threads exactly).
// R6: 139us = 5.89 TB/s (93.6% of 6.29 TB/s copy ceiling).
// R7 single-variable test: nontemporal load+store (stream-once both ways,
// skip cache allocation). R4/R5 showed nt helped the unrolled variant;
// testing it unconfounded on the exact-fit shape.

typedef float f32x4 __attribute__((ext_vector_type(4)));

__global__ __launch_bounds__(256) void colscale_kernel(
    const f32x4* __restrict__ x4,
    const f32x4* __restrict__ w4,    // 128 f32x4 (512 floats), L1/L2 resident
    f32x4* __restrict__ out4,
    long long n4)
{
    long long i = (long long)blockIdx.x * blockDim.x + threadIdx.x;
    if (i < n4) {
        f32x4 v = __builtin_nontemporal_load(&x4[i]);
        v *= w4[(int)(i & 127)];
        __builtin_nontemporal_store(v, &out4[i]);
    }
}

extern "C" void kernel_launch(void* const* d_in, const int* in_sizes, int n_in,
                              void* d_out, int out_size, void* d_ws, size_t ws_size,
                              hipStream_t stream) {
    const f32x4* x4 = (const f32x4*)d_in[0];            // x: [N, D] fp32
    const f32x4* w4 = (const f32x4*)d_in[1];            // weight_local: [D,1] fp32
    f32x4* out4 = (f32x4*)d_out;

    long long n4 = (long long)out_size / 4;             // 25,600,000
    const int block = 256;
    long long grid = (n4 + block - 1) / block;          // 100000 exactly

    colscale_kernel<<<(int)grid, block, 0, stream>>>(x4, w4, out4, n4);
}